// Round 2
// baseline (1074.138 us; speedup 1.0000x reference)
//
#include <hip/hip_runtime.h>
#include <hip/hip_bf16.h>

typedef __bf16 bf16_t;
typedef __bf16 bf16x8 __attribute__((ext_vector_type(8)));
typedef __bf16 bf16x4 __attribute__((ext_vector_type(4)));
typedef __bf16 bf16x2 __attribute__((ext_vector_type(2)));
typedef float f32x4 __attribute__((ext_vector_type(4)));

#define MFMA16(a,b,c) __builtin_amdgcn_mfma_f32_16x16x32_bf16((a),(b),(c),0,0,0)

constexpr int B_ = 4, L_ = 2048, E_ = 2048, H_ = 16, HD_ = 128;
constexpr size_t QK_ELEMS = (size_t)B_ * H_ * L_ * HD_;  // 16,777,216

// ---------------------------------------------------------------------------
// Kernel 1: y = x @ W^T + b  (fp32 inputs, bf16 MFMA compute)
// 128x128 tile, BK=32, 4 waves 2x2. Epilogue scatters q,k -> [B,H,L,HD] bf16
// and v -> vT [B,H,HD,L] bf16 (transposed at store; saves a transpose kernel).
// n-tile of 128 lies entirely inside one (h, which) 384-block since 3*HD=384.
// ---------------------------------------------------------------------------
__global__ __launch_bounds__(256) void gemm_qkv(
    const float* __restrict__ X, const float* __restrict__ W, const float* __restrict__ bias,
    bf16_t* __restrict__ q, bf16_t* __restrict__ k, bf16_t* __restrict__ vT)
{
  __shared__ alignas(16) bf16_t As[128 * 32];   // [m][k]
  __shared__ alignas(16) bf16_t Bs[128 * 32];   // [n][k]
  const int tid = threadIdx.x;
  const int wave = tid >> 6, lane = tid & 63;
  const int wm = wave >> 1, wn = wave & 1;
  const int m0 = blockIdx.y * 128, n0 = blockIdx.x * 128;
  const int rowf = lane & 15, kq8 = (lane >> 4) * 8;

  const f32x4 fzero = {0.f, 0.f, 0.f, 0.f};
  f32x4 acc[4][4];
  for (int i = 0; i < 4; ++i)
    for (int j = 0; j < 4; ++j) acc[i][j] = fzero;

  for (int k0 = 0; k0 < E_; k0 += 32) {
    __syncthreads();
    // stage fp32 -> bf16: 4 passes x 256 threads x 4 elems (float4 load, b64 LDS write)
    for (int p = 0; p < 4; ++p) {
      int e = (p * 256 + tid) * 4;
      int r = e >> 5, c = e & 31;
      f32x4 xa = *(const f32x4*)&X[(size_t)(m0 + r) * E_ + k0 + c];
      f32x4 wa = *(const f32x4*)&W[(size_t)(n0 + r) * E_ + k0 + c];
      bf16x4 xb, wb;
      for (int u = 0; u < 4; ++u) { xb[u] = (__bf16)xa[u]; wb[u] = (__bf16)wa[u]; }
      *(bf16x4*)&As[e] = xb;
      *(bf16x4*)&Bs[e] = wb;
    }
    __syncthreads();
    bf16x8 af[4], bfr[4];
    for (int mt = 0; mt < 4; ++mt) af[mt]  = *(const bf16x8*)&As[(wm * 64 + mt * 16 + rowf) * 32 + kq8];
    for (int nt = 0; nt < 4; ++nt) bfr[nt] = *(const bf16x8*)&Bs[(wn * 64 + nt * 16 + rowf) * 32 + kq8];
    for (int mt = 0; mt < 4; ++mt)
      for (int nt = 0; nt < 4; ++nt)
        acc[mt][nt] = MFMA16(af[mt], bfr[nt], acc[mt][nt]);
  }

  const int b  = m0 >> 11;            // m0 / 2048
  const int l0 = m0 & (L_ - 1);
  const int h  = n0 / 384;
  const int which = (n0 % 384) >> 7;  // 0=q 1=k 2=v

  float bcol[4];
  for (int nt = 0; nt < 4; ++nt)
    bcol[nt] = bias[n0 + wn * 64 + nt * 16 + (lane & 15)];

  if (which < 2) {
    bf16_t* base = ((which == 0) ? q : k) + ((size_t)(b * H_ + h) * L_) * HD_;
    for (int mt = 0; mt < 4; ++mt)
      for (int r = 0; r < 4; ++r) {
        int l = l0 + wm * 64 + mt * 16 + ((lane >> 4) << 2) + r;  // C/D row = (lane>>4)*4 + r
        bf16_t* rowp = base + (size_t)l * HD_;
        for (int nt = 0; nt < 4; ++nt) {
          int hd = wn * 64 + nt * 16 + (lane & 15);               // C/D col = lane&15
          rowp[hd] = (__bf16)(acc[mt][nt][r] + bcol[nt]);
        }
      }
  } else {
    bf16_t* base = vT + ((size_t)(b * H_ + h) * HD_) * L_;
    for (int mt = 0; mt < 4; ++mt)
      for (int r = 0; r < 4; ++r) {
        int l = l0 + wm * 64 + mt * 16 + ((lane >> 4) << 2) + r;
        for (int nt = 0; nt < 4; ++nt) {
          int hd = wn * 64 + nt * 16 + (lane & 15);
          base[(size_t)hd * L_ + l] = (__bf16)(acc[mt][nt][r] + bcol[nt]);
        }
      }
  }
}

// ---------------------------------------------------------------------------
// Kernel 2: in-place L2 normalize each 128-elem row of q and k (1 wave/row)
// ---------------------------------------------------------------------------
__global__ __launch_bounds__(256) void norm_qk(bf16_t* __restrict__ q, bf16_t* __restrict__ kk)
{
  const int gw = blockIdx.x * 4 + (threadIdx.x >> 6);
  const int lane = threadIdx.x & 63;
  const int rows_per = B_ * H_ * L_;  // 131072
  bf16_t* base = (gw < rows_per) ? q : kk;
  int row = (gw < rows_per) ? gw : gw - rows_per;
  bf16_t* p = base + (size_t)row * HD_ + lane * 2;
  bf16x2 v2 = *(const bf16x2*)p;
  float a = (float)v2.x, bb = (float)v2.y;
  float ss = a * a + bb * bb;
  for (int off = 32; off; off >>= 1) ss += __shfl_xor(ss, off);
  float sc = 1.0f / fmaxf(sqrtf(ss), 1e-12f);  // matches F.normalize eps
  v2.x = (__bf16)(a * sc);
  v2.y = (__bf16)(bb * sc);
  *(bf16x2*)p = v2;
}

// ---------------------------------------------------------------------------
// Kernel 3: flash-style attention. BQ=128, BKV=64, 4 waves (32 q-rows each).
// LDS: Qs 32KB + KPs 16KB (Ks aliased with Ps) + Vts 16KB = 64KB -> 2 blk/CU.
// XOR-swizzled 16B chunks to kill 16-way row-stride bank conflicts.
// Output written as fp32 [B,L,H,HD].
// ---------------------------------------------------------------------------
__device__ __forceinline__ int swz128(int r, int c) {
  return r * 128 + ((((c >> 3) ^ (r & 15)) & 15) << 3) + (c & 7);
}
__device__ __forceinline__ int swz64(int r, int c) {
  return r * 64 + ((((c >> 3) ^ (r & 7)) & 7) << 3) + (c & 7);
}

__global__ __launch_bounds__(256) void attn(
    const bf16_t* __restrict__ q, const bf16_t* __restrict__ k,
    const bf16_t* __restrict__ vT, float* __restrict__ out)
{
  __shared__ alignas(16) bf16_t Qs[128 * 128];
  __shared__ alignas(16) bf16_t KPs[64 * 128];  // Ks[64][128] during QK^T; Ps[128][64] during PV
  __shared__ alignas(16) bf16_t Vts[128 * 64];  // [d][j]

  const int tid = threadIdx.x, wave = tid >> 6, lane = tid & 63;
  const int bh = blockIdx.y;
  const int q0 = blockIdx.x * 128;
  const int rowf = lane & 15, kq8 = (lane >> 4) * 8;

  const bf16_t* qbase = q + ((size_t)bh * L_ + q0) * HD_;
  for (int i = 0; i < 8; ++i) {
    int e = (i * 256 + tid) * 8;
    *(f32x4*)&Qs[swz128(e >> 7, e & 127)] = *(const f32x4*)&qbase[e];
  }

  const f32x4 fzero = {0.f, 0.f, 0.f, 0.f};
  f32x4 o[2][8];
  for (int mt = 0; mt < 2; ++mt)
    for (int nt = 0; nt < 8; ++nt) o[mt][nt] = fzero;
  float mrow[2][4], lrow[2][4];
  for (int mt = 0; mt < 2; ++mt)
    for (int r = 0; r < 4; ++r) { mrow[mt][r] = -1e30f; lrow[mt][r] = 0.f; }

  const bf16_t* kbh = k + (size_t)bh * L_ * HD_;
  const bf16_t* vbh = vT + (size_t)bh * HD_ * L_;

  for (int j0 = 0; j0 < L_; j0 += 64) {
    __syncthreads();  // guard KPs/Vts restage vs previous iteration's reads
    for (int i = 0; i < 4; ++i) {
      int e = (i * 256 + tid) * 8;
      *(f32x4*)&KPs[swz128(e >> 7, e & 127)] = *(const f32x4*)&kbh[(size_t)j0 * HD_ + e];
    }
    for (int i = 0; i < 4; ++i) {
      int e = (i * 256 + tid) * 8;
      int d = e >> 6, c = e & 63;
      *(f32x4*)&Vts[swz64(d, c)] = *(const f32x4*)&vbh[(size_t)d * L_ + j0 + c];
    }
    __syncthreads();

    // S = Q K^T (both operands row-major along d)
    f32x4 s[2][4];
    for (int mt = 0; mt < 2; ++mt)
      for (int nt = 0; nt < 4; ++nt) s[mt][nt] = fzero;
    for (int kk = 0; kk < 128; kk += 32) {
      bf16x8 aq[2], bk4[4];
      for (int mt = 0; mt < 2; ++mt) aq[mt]  = *(const bf16x8*)&Qs[swz128(wave * 32 + mt * 16 + rowf, kk + kq8)];
      for (int nt = 0; nt < 4; ++nt) bk4[nt] = *(const bf16x8*)&KPs[swz128(nt * 16 + rowf, kk + kq8)];
      for (int mt = 0; mt < 2; ++mt)
        for (int nt = 0; nt < 4; ++nt)
          s[mt][nt] = MFMA16(aq[mt], bk4[nt], s[mt][nt]);
    }
    __syncthreads();  // all waves done reading Ks before it becomes Ps

    // online softmax: S and O share row mapping (lane>>4)*4+r
    for (int mt = 0; mt < 2; ++mt) {
      for (int r = 0; r < 4; ++r) {
        float mx = fmaxf(fmaxf(s[mt][0][r], s[mt][1][r]), fmaxf(s[mt][2][r], s[mt][3][r]));
        for (int off = 8; off; off >>= 1) mx = fmaxf(mx, __shfl_xor(mx, off));
        float mnew = fmaxf(mrow[mt][r], mx);
        float alpha = __expf(mrow[mt][r] - mnew);
        mrow[mt][r] = mnew;
        float ps = 0.f;
        for (int nt = 0; nt < 4; ++nt) {
          float p0 = __expf(s[mt][nt][r] - mnew);
          s[mt][nt][r] = p0;
          ps += p0;
        }
        for (int off = 8; off; off >>= 1) ps += __shfl_xor(ps, off);
        lrow[mt][r] = lrow[mt][r] * alpha + ps;
        for (int nt = 0; nt < 8; ++nt) o[mt][nt][r] *= alpha;
      }
    }
    // P: C-layout regs -> A-layout via LDS round-trip (bf16)
    for (int mt = 0; mt < 2; ++mt)
      for (int nt = 0; nt < 4; ++nt)
        for (int r = 0; r < 4; ++r) {
          int rr = wave * 32 + mt * 16 + ((lane >> 4) << 2) + r;
          int cc = nt * 16 + (lane & 15);
          KPs[swz64(rr, cc)] = (__bf16)s[mt][nt][r];
        }
    __syncthreads();

    // O += P @ V
    for (int kk = 0; kk < 64; kk += 32) {
      bf16x8 ap[2];
      for (int mt = 0; mt < 2; ++mt)
        ap[mt] = *(const bf16x8*)&KPs[swz64(wave * 32 + mt * 16 + rowf, kk + kq8)];
      for (int nt = 0; nt < 8; ++nt) {
        bf16x8 bvv = *(const bf16x8*)&Vts[swz64(nt * 16 + rowf, kk + kq8)];
        for (int mt = 0; mt < 2; ++mt)
          o[mt][nt] = MFMA16(ap[mt], bvv, o[mt][nt]);
      }
    }
  }

  // epilogue: divide by softmax denom, write fp32 out [B][L][H][HD]
  const int b = bh >> 4, h = bh & 15;
  for (int mt = 0; mt < 2; ++mt) {
    for (int r = 0; r < 4; ++r) {
      float inv = 1.0f / lrow[mt][r];
      int l = q0 + wave * 32 + mt * 16 + ((lane >> 4) << 2) + r;
      float* op = out + (((size_t)b * L_ + l) * H_ + h) * HD_;
      for (int nt = 0; nt < 8; ++nt) {
        int d = nt * 16 + (lane & 15);
        op[d] = o[mt][nt][r] * inv;
      }
    }
  }
}

// ---------------------------------------------------------------------------
extern "C" void kernel_launch(void* const* d_in, const int* in_sizes, int n_in,
                              void* d_out, int out_size, void* d_ws, size_t ws_size,
                              hipStream_t stream)
{
  const float* X    = (const float*)d_in[0];   // [4,2048,2048] fp32
  const float* W    = (const float*)d_in[1];   // [6144,2048] fp32
  const float* bias = (const float*)d_in[2];   // [6144] fp32
  float* out = (float*)d_out;                  // [4,2048,2048] fp32

  bf16_t* q  = (bf16_t*)d_ws;                  // [B,H,L,HD] 32MB
  bf16_t* k  = q + QK_ELEMS;                   // 32MB
  bf16_t* vT = k + QK_ELEMS;                   // [B,H,HD,L] 32MB

  gemm_qkv<<<dim3(48, 64), 256, 0, stream>>>(X, W, bias, q, k, vT);
  norm_qk<<<dim3(65536), 256, 0, stream>>>(q, k);
  attn<<<dim3(16, 64), 256, 0, stream>>>(q, k, vT, out);
}

// Round 3
// 834.289 us; speedup vs baseline: 1.2875x; 1.2875x over previous
//
#include <hip/hip_runtime.h>
#include <hip/hip_bf16.h>

typedef __bf16 bf16_t;
typedef __bf16 bf16x8 __attribute__((ext_vector_type(8)));
typedef __bf16 bf16x4 __attribute__((ext_vector_type(4)));
typedef __bf16 bf16x2 __attribute__((ext_vector_type(2)));
typedef float f32x4 __attribute__((ext_vector_type(4)));

#define MFMA16(a,b,c) __builtin_amdgcn_mfma_f32_16x16x32_bf16((a),(b),(c),0,0,0)
#define AS3(p) ((__attribute__((address_space(3))) void*)(p))
#define AS1(p) ((const __attribute__((address_space(1))) void*)(p))

constexpr int B_ = 4, L_ = 2048, E_ = 2048, H_ = 16, HD_ = 128;
constexpr size_t QK_ELEMS = (size_t)B_ * H_ * L_ * HD_;    // 16,777,216
constexpr size_t NX = (size_t)B_ * L_ * E_;                // 16,777,216
constexpr size_t NW = (size_t)3 * E_ * E_;                 // 12,582,912

// ---------------------------------------------------------------------------
// Kernel 0: fp32 -> bf16 conversion of X and W into one contiguous dst
// (dst lives in d_out's first 58.7MB; overwritten later by attn's output).
// ---------------------------------------------------------------------------
__global__ __launch_bounds__(256) void cvt(
    const float* __restrict__ X, const float* __restrict__ W, bf16_t* __restrict__ dst)
{
  size_t e = ((size_t)blockIdx.x * 256 + threadIdx.x) * 4;
  f32x4 v = (e < NX) ? *(const f32x4*)&X[e] : *(const f32x4*)&W[e - NX];
  bf16x4 o;
  for (int u = 0; u < 4; ++u) o[u] = (__bf16)v[u];
  *(bf16x4*)&dst[e] = o;
}

// ---------------------------------------------------------------------------
// Kernel 1: y = Xb @ Wb^T + b  (bf16 inputs, m97 structure)
// 128x128 tile, BK=32, 4 waves 2x2, global_load_lds width=16 staging.
// Epilogue scatters q,k -> [B,H,L,HD] and v -> vT [B,H,HD,L] (bf16).
// n-tile of 128 lies entirely inside one (h, which) 384-block since 3*HD=384.
// ---------------------------------------------------------------------------
__global__ __launch_bounds__(256) void gemm_qkv(
    const bf16_t* __restrict__ Xb, const bf16_t* __restrict__ Wb, const float* __restrict__ bias,
    bf16_t* __restrict__ q, bf16_t* __restrict__ k, bf16_t* __restrict__ vT)
{
  __shared__ alignas(16) bf16_t As[128 * 32];   // [m][k] packed, 64B rows
  __shared__ alignas(16) bf16_t Bs[128 * 32];   // [n][k] packed
  const int tid = threadIdx.x;
  const int wave = tid >> 6, lane = tid & 63;
  const int wm = wave >> 1, wn = wave & 1;
  const int m0 = blockIdx.y * 128, n0 = blockIdx.x * 128;
  const int rowf = lane & 15, kq8 = (lane >> 4) * 8;

  // staging: wave w owns rows [w*32, w*32+32) of A and B, 2 insts x 16 rows.
  // lane i covers row (i>>2), 16B chunk (i&3) -- LDS dest = base + i*16,
  // which lands exactly at As[row*32 + (i&3)*8] (contiguous [row][32] layout).
  const int srow = wave * 32 + (lane >> 2);
  const int scol = (lane & 3) * 8;
  const bf16_t* gA0 = &Xb[(size_t)(m0 + srow) * E_ + scol];
  const bf16_t* gB0 = &Wb[(size_t)(n0 + srow) * E_ + scol];
  bf16_t* lA0 = &As[(wave * 32) * 32];
  bf16_t* lA1 = &As[(wave * 32 + 16) * 32];
  bf16_t* lB0 = &Bs[(wave * 32) * 32];
  bf16_t* lB1 = &Bs[(wave * 32 + 16) * 32];

  const f32x4 fzero = {0.f, 0.f, 0.f, 0.f};
  f32x4 acc[4][4];
  for (int i = 0; i < 4; ++i)
    for (int j = 0; j < 4; ++j) acc[i][j] = fzero;

  for (int k0 = 0; k0 < E_; k0 += 32) {
    __syncthreads();
    __builtin_amdgcn_global_load_lds(AS1(gA0 + k0),            AS3(lA0), 16, 0, 0);
    __builtin_amdgcn_global_load_lds(AS1(gA0 + 16 * E_ + k0),  AS3(lA1), 16, 0, 0);
    __builtin_amdgcn_global_load_lds(AS1(gB0 + k0),            AS3(lB0), 16, 0, 0);
    __builtin_amdgcn_global_load_lds(AS1(gB0 + 16 * E_ + k0),  AS3(lB1), 16, 0, 0);
    __syncthreads();
    bf16x8 af[4], bfr[4];
    for (int mt = 0; mt < 4; ++mt) af[mt]  = *(const bf16x8*)&As[(wm * 64 + mt * 16 + rowf) * 32 + kq8];
    for (int nt = 0; nt < 4; ++nt) bfr[nt] = *(const bf16x8*)&Bs[(wn * 64 + nt * 16 + rowf) * 32 + kq8];
    for (int mt = 0; mt < 4; ++mt)
      for (int nt = 0; nt < 4; ++nt)
        acc[mt][nt] = MFMA16(af[mt], bfr[nt], acc[mt][nt]);
  }

  const int b  = m0 >> 11;            // m0 / 2048
  const int l0 = m0 & (L_ - 1);
  const int h  = n0 / 384;
  const int which = (n0 % 384) >> 7;  // 0=q 1=k 2=v

  float bcol[4];
  for (int nt = 0; nt < 4; ++nt)
    bcol[nt] = bias[n0 + wn * 64 + nt * 16 + (lane & 15)];

  if (which < 2) {
    bf16_t* base = ((which == 0) ? q : k) + ((size_t)(b * H_ + h) * L_) * HD_;
    for (int mt = 0; mt < 4; ++mt)
      for (int r = 0; r < 4; ++r) {
        int l = l0 + wm * 64 + mt * 16 + ((lane >> 4) << 2) + r;  // C/D row = (lane>>4)*4 + r
        bf16_t* rowp = base + (size_t)l * HD_;
        for (int nt = 0; nt < 4; ++nt) {
          int hd = wn * 64 + nt * 16 + (lane & 15);               // C/D col = lane&15
          rowp[hd] = (__bf16)(acc[mt][nt][r] + bcol[nt]);
        }
      }
  } else {
    bf16_t* base = vT + ((size_t)(b * H_ + h) * HD_) * L_;
    for (int mt = 0; mt < 4; ++mt)
      for (int r = 0; r < 4; ++r) {
        int l = l0 + wm * 64 + mt * 16 + ((lane >> 4) << 2) + r;
        for (int nt = 0; nt < 4; ++nt) {
          int hd = wn * 64 + nt * 16 + (lane & 15);
          base[(size_t)hd * L_ + l] = (__bf16)(acc[mt][nt][r] + bcol[nt]);
        }
      }
  }
}

// ---------------------------------------------------------------------------
// Kernel 2: in-place L2 normalize each 128-elem row of q and k (1 wave/row)
// ---------------------------------------------------------------------------
__global__ __launch_bounds__(256) void norm_qk(bf16_t* __restrict__ q, bf16_t* __restrict__ kk)
{
  const int gw = blockIdx.x * 4 + (threadIdx.x >> 6);
  const int lane = threadIdx.x & 63;
  const int rows_per = B_ * H_ * L_;  // 131072
  bf16_t* base = (gw < rows_per) ? q : kk;
  int row = (gw < rows_per) ? gw : gw - rows_per;
  bf16_t* p = base + (size_t)row * HD_ + lane * 2;
  bf16x2 v2 = *(const bf16x2*)p;
  float a = (float)v2.x, bb = (float)v2.y;
  float ss = a * a + bb * bb;
  for (int off = 32; off; off >>= 1) ss += __shfl_xor(ss, off);
  float sc = 1.0f / fmaxf(sqrtf(ss), 1e-12f);  // matches F.normalize eps
  v2.x = (__bf16)(a * sc);
  v2.y = (__bf16)(bb * sc);
  *(bf16x2*)p = v2;
}

// ---------------------------------------------------------------------------
// Kernel 3: flash-style attention. BQ=128, BKV=64, 4 waves (32 q-rows each).
// LDS: Qs 32KB + KPs 16KB (Ks aliased with Ps) + Vts 16KB = 64KB -> 2 blk/CU.
// XOR-swizzled 16B chunks to kill 16-way row-stride bank conflicts.
// Output written as fp32 [B,L,H,HD].
// ---------------------------------------------------------------------------
__device__ __forceinline__ int swz128(int r, int c) {
  return r * 128 + ((((c >> 3) ^ (r & 15)) & 15) << 3) + (c & 7);
}
__device__ __forceinline__ int swz64(int r, int c) {
  return r * 64 + ((((c >> 3) ^ (r & 7)) & 7) << 3) + (c & 7);
}

__global__ __launch_bounds__(256) void attn(
    const bf16_t* __restrict__ q, const bf16_t* __restrict__ k,
    const bf16_t* __restrict__ vT, float* __restrict__ out)
{
  __shared__ alignas(16) bf16_t Qs[128 * 128];
  __shared__ alignas(16) bf16_t KPs[64 * 128];  // Ks[64][128] during QK^T; Ps[128][64] during PV
  __shared__ alignas(16) bf16_t Vts[128 * 64];  // [d][j]

  const int tid = threadIdx.x, wave = tid >> 6, lane = tid & 63;
  const int bh = blockIdx.y;
  const int q0 = blockIdx.x * 128;
  const int rowf = lane & 15, kq8 = (lane >> 4) * 8;

  const bf16_t* qbase = q + ((size_t)bh * L_ + q0) * HD_;
  for (int i = 0; i < 8; ++i) {
    int e = (i * 256 + tid) * 8;
    *(f32x4*)&Qs[swz128(e >> 7, e & 127)] = *(const f32x4*)&qbase[e];
  }

  const f32x4 fzero = {0.f, 0.f, 0.f, 0.f};
  f32x4 o[2][8];
  for (int mt = 0; mt < 2; ++mt)
    for (int nt = 0; nt < 8; ++nt) o[mt][nt] = fzero;
  float mrow[2][4], lrow[2][4];
  for (int mt = 0; mt < 2; ++mt)
    for (int r = 0; r < 4; ++r) { mrow[mt][r] = -1e30f; lrow[mt][r] = 0.f; }

  const bf16_t* kbh = k + (size_t)bh * L_ * HD_;
  const bf16_t* vbh = vT + (size_t)bh * HD_ * L_;

  for (int j0 = 0; j0 < L_; j0 += 64) {
    __syncthreads();  // guard KPs/Vts restage vs previous iteration's reads
    for (int i = 0; i < 4; ++i) {
      int e = (i * 256 + tid) * 8;
      *(f32x4*)&KPs[swz128(e >> 7, e & 127)] = *(const f32x4*)&kbh[(size_t)j0 * HD_ + e];
    }
    for (int i = 0; i < 4; ++i) {
      int e = (i * 256 + tid) * 8;
      int d = e >> 6, c = e & 63;
      *(f32x4*)&Vts[swz64(d, c)] = *(const f32x4*)&vbh[(size_t)d * L_ + j0 + c];
    }
    __syncthreads();

    // S = Q K^T (both operands row-major along d)
    f32x4 s[2][4];
    for (int mt = 0; mt < 2; ++mt)
      for (int nt = 0; nt < 4; ++nt) s[mt][nt] = fzero;
    for (int kk = 0; kk < 128; kk += 32) {
      bf16x8 aq[2], bk4[4];
      for (int mt = 0; mt < 2; ++mt) aq[mt]  = *(const bf16x8*)&Qs[swz128(wave * 32 + mt * 16 + rowf, kk + kq8)];
      for (int nt = 0; nt < 4; ++nt) bk4[nt] = *(const bf16x8*)&KPs[swz128(nt * 16 + rowf, kk + kq8)];
      for (int mt = 0; mt < 2; ++mt)
        for (int nt = 0; nt < 4; ++nt)
          s[mt][nt] = MFMA16(aq[mt], bk4[nt], s[mt][nt]);
    }
    __syncthreads();  // all waves done reading Ks before it becomes Ps

    // online softmax: S and O share row mapping (lane>>4)*4+r
    for (int mt = 0; mt < 2; ++mt) {
      for (int r = 0; r < 4; ++r) {
        float mx = fmaxf(fmaxf(s[mt][0][r], s[mt][1][r]), fmaxf(s[mt][2][r], s[mt][3][r]));
        for (int off = 8; off; off >>= 1) mx = fmaxf(mx, __shfl_xor(mx, off));
        float mnew = fmaxf(mrow[mt][r], mx);
        float alpha = __expf(mrow[mt][r] - mnew);
        mrow[mt][r] = mnew;
        float ps = 0.f;
        for (int nt = 0; nt < 4; ++nt) {
          float p0 = __expf(s[mt][nt][r] - mnew);
          s[mt][nt][r] = p0;
          ps += p0;
        }
        for (int off = 8; off; off >>= 1) ps += __shfl_xor(ps, off);
        lrow[mt][r] = lrow[mt][r] * alpha + ps;
        for (int nt = 0; nt < 8; ++nt) o[mt][nt][r] *= alpha;
      }
    }
    // P: C-layout regs -> A-layout via LDS round-trip (bf16)
    for (int mt = 0; mt < 2; ++mt)
      for (int nt = 0; nt < 4; ++nt)
        for (int r = 0; r < 4; ++r) {
          int rr = wave * 32 + mt * 16 + ((lane >> 4) << 2) + r;
          int cc = nt * 16 + (lane & 15);
          KPs[swz64(rr, cc)] = (__bf16)s[mt][nt][r];
        }
    __syncthreads();

    // O += P @ V
    for (int kk = 0; kk < 64; kk += 32) {
      bf16x8 ap[2];
      for (int mt = 0; mt < 2; ++mt)
        ap[mt] = *(const bf16x8*)&KPs[swz64(wave * 32 + mt * 16 + rowf, kk + kq8)];
      for (int nt = 0; nt < 8; ++nt) {
        bf16x8 bvv = *(const bf16x8*)&Vts[swz64(nt * 16 + rowf, kk + kq8)];
        for (int mt = 0; mt < 2; ++mt)
          o[mt][nt] = MFMA16(ap[mt], bvv, o[mt][nt]);
      }
    }
  }

  // epilogue: divide by softmax denom, write fp32 out [B][L][H][HD]
  const int b = bh >> 4, h = bh & 15;
  for (int mt = 0; mt < 2; ++mt) {
    for (int r = 0; r < 4; ++r) {
      float inv = 1.0f / lrow[mt][r];
      int l = q0 + wave * 32 + mt * 16 + ((lane >> 4) << 2) + r;
      float* op = out + (((size_t)b * L_ + l) * H_ + h) * HD_;
      for (int nt = 0; nt < 8; ++nt) {
        int d = nt * 16 + (lane & 15);
        op[d] = o[mt][nt][r] * inv;
      }
    }
  }
}

// ---------------------------------------------------------------------------
extern "C" void kernel_launch(void* const* d_in, const int* in_sizes, int n_in,
                              void* d_out, int out_size, void* d_ws, size_t ws_size,
                              hipStream_t stream)
{
  const float* X    = (const float*)d_in[0];   // [4,2048,2048] fp32
  const float* W    = (const float*)d_in[1];   // [6144,2048] fp32
  const float* bias = (const float*)d_in[2];   // [6144] fp32
  float* out = (float*)d_out;                  // [4,2048,2048] fp32

  // bf16 copies of X and W live inside d_out (58.7MB < 67.1MB); d_out is not
  // written by anything until attn, which runs after gemm_qkv has consumed them.
  bf16_t* Xb = (bf16_t*)d_out;
  bf16_t* Wb = Xb + NX;

  bf16_t* q  = (bf16_t*)d_ws;                  // [B,H,L,HD] 32MB
  bf16_t* k  = q + QK_ELEMS;                   // 32MB
  bf16_t* vT = k + QK_ELEMS;                   // [B,H,HD,L] 32MB

  cvt<<<dim3((NX + NW) / (256 * 4)), 256, 0, stream>>>(X, W, Xb);
  gemm_qkv<<<dim3(48, 64), 256, 0, stream>>>(Xb, Wb, bias, q, k, vT);
  norm_qk<<<dim3(65536), 256, 0, stream>>>(q, k);
  attn<<<dim3(16, 64), 256, 0, stream>>>(q, k, vT, out);
}